// Round 1
// baseline (619.621 us; speedup 1.0000x reference)
//
#include <hip/hip_runtime.h>
#include <hip/hip_bf16.h>

#define N_NODES 50000
#define N_EDGES 300000
#define DIM 256

typedef __attribute__((ext_vector_type(4))) float f32x4;
typedef __attribute__((ext_vector_type(8))) __bf16 bf16x8;
typedef __attribute__((ext_vector_type(4))) __bf16 bf16x4;

// ---------------- weight prep: transpose + bf16 convert ----------------
// Wt_cat[n][k] = Wsel[k][n&255] for n in [0,1024): sel = q,k,v,skip
// Wt_e[n][k]   = We[k][n]
__global__ void prep_weights_kernel(const float* __restrict__ Wq, const float* __restrict__ bq,
                                    const float* __restrict__ Wk, const float* __restrict__ bk,
                                    const float* __restrict__ Wv, const float* __restrict__ bv,
                                    const float* __restrict__ Wskip, const float* __restrict__ bskip,
                                    const float* __restrict__ We,
                                    __bf16* __restrict__ Wt_cat, float* __restrict__ bias_cat,
                                    __bf16* __restrict__ Wt_e) {
    int idx = blockIdx.x * 256 + threadIdx.x;
    if (idx < 1024 * 256) {
        int n = idx >> 8, kk = idx & 255;
        int sel = n >> 8, nn = n & 255;
        const float* W = sel == 0 ? Wq : sel == 1 ? Wk : sel == 2 ? Wv : Wskip;
        Wt_cat[idx] = (__bf16)W[kk * 256 + nn];
        if (kk == 0) {
            const float* b = sel == 0 ? bq : sel == 1 ? bk : sel == 2 ? bv : bskip;
            bias_cat[n] = b[nn];
        }
    } else {
        int j = idx - 1024 * 256;
        if (j < 256 * 256) {
            int n = j >> 8, kk = j & 255;
            Wt_e[j] = (__bf16)We[kk * 256 + n];
        }
    }
}

// ---------------- CSR build ----------------
__global__ void count_kernel(const int* __restrict__ dst, int* __restrict__ counts) {
    int i = blockIdx.x * 256 + threadIdx.x;
    if (i < N_EDGES) atomicAdd(&counts[dst[i]], 1);
}

__global__ void scan_kernel(const int* __restrict__ counts, int* __restrict__ row_ptr,
                            int* __restrict__ cursor) {
    const int T = 1024;
    const int CPT = (N_NODES + T - 1) / T;  // 49
    int tid = threadIdx.x;
    int base = tid * CPT;
    int s = 0;
    for (int j = 0; j < CPT; j++) {
        int idx = base + j;
        if (idx < N_NODES) s += counts[idx];
    }
    __shared__ int buf[T];
    buf[tid] = s;
    __syncthreads();
    for (int off = 1; off < T; off <<= 1) {
        int t = (tid >= off) ? buf[tid - off] : 0;
        __syncthreads();
        buf[tid] += t;
        __syncthreads();
    }
    int run = buf[tid] - s;  // exclusive prefix for this chunk
    for (int j = 0; j < CPT; j++) {
        int idx = base + j;
        if (idx < N_NODES) {
            row_ptr[idx] = run;
            cursor[idx] = run;
            run += counts[idx];
        }
    }
    if (tid == T - 1) row_ptr[N_NODES] = run;
}

__global__ void scatter_kernel(const int* __restrict__ dst, int* __restrict__ cursor,
                               int* __restrict__ cidx) {
    int i = blockIdx.x * 256 + threadIdx.x;
    if (i < N_EDGES) {
        int p = atomicAdd(&cursor[dst[i]], 1);
        cidx[p] = i;
    }
}

// ---------------- bf16 MFMA GEMM: C[M][Nout] = A[M][256] @ Wt^T (+bias) ----------------
// Wt is [Nout][256] (already transposed), bf16. A is f32, converted while staging.
// Tile: BM=64, BN=256, BK=32. 512 threads = 8 waves in 2x4 grid, each wave 32x64.
#define BM 64
#define BN 256
#define BK 32
#define KDIM 256

template <typename OutT>
__global__ __launch_bounds__(512) void gemm_kernel(const float* __restrict__ A, int M,
                                                   const __bf16* __restrict__ Wt,
                                                   const float* __restrict__ bias, int Nout,
                                                   OutT* __restrict__ C) {
    __shared__ __bf16 As[BM][BK + 8];   // +8 pad: keeps 16B alignment, spreads banks
    __shared__ __bf16 Bs[BN][BK + 8];
    int tid = threadIdx.x;
    int m0 = blockIdx.x * BM;
    int n0 = blockIdx.y * BN;
    int lane = tid & 63, w = tid >> 6;
    int wr = w >> 2, wc = w & 3;        // wave grid 2 x 4
    int l15 = lane & 15, kg = lane >> 4;

    f32x4 acc[2][4];
#pragma unroll
    for (int r = 0; r < 2; r++)
#pragma unroll
        for (int c = 0; c < 4; c++) acc[r][c] = (f32x4)0.f;

    int arow = tid >> 3, apart = tid & 7;  // A stage: 64 rows x 8 parts of 4 floats
    int brow = tid >> 1, bpart = tid & 1;  // B stage: 256 rows x 2 parts of 16 bf16
    bool aok = (m0 + arow) < M;
    const float* Aptr = A + (size_t)(m0 + arow) * KDIM + apart * 4;
    const __bf16* Bptr = Wt + (size_t)(n0 + brow) * KDIM + bpart * 16;

    for (int k0 = 0; k0 < KDIM; k0 += BK) {
        f32x4 av = aok ? *reinterpret_cast<const f32x4*>(Aptr + k0) : (f32x4)0.f;
        bf16x4 ab;
        ab.x = (__bf16)av.x; ab.y = (__bf16)av.y; ab.z = (__bf16)av.z; ab.w = (__bf16)av.w;
        *reinterpret_cast<bf16x4*>(&As[arow][apart * 4]) = ab;

        bf16x8 b0 = *reinterpret_cast<const bf16x8*>(Bptr + k0);
        bf16x8 b1 = *reinterpret_cast<const bf16x8*>(Bptr + k0 + 8);
        *reinterpret_cast<bf16x8*>(&Bs[brow][bpart * 16]) = b0;
        *reinterpret_cast<bf16x8*>(&Bs[brow][bpart * 16 + 8]) = b1;
        __syncthreads();

        bf16x8 af[2], bfr[4];
#pragma unroll
        for (int r = 0; r < 2; r++)
            af[r] = *reinterpret_cast<const bf16x8*>(&As[wr * 32 + r * 16 + l15][kg * 8]);
#pragma unroll
        for (int c = 0; c < 4; c++)
            bfr[c] = *reinterpret_cast<const bf16x8*>(&Bs[wc * 64 + c * 16 + l15][kg * 8]);
#pragma unroll
        for (int r = 0; r < 2; r++)
#pragma unroll
            for (int c = 0; c < 4; c++)
                acc[r][c] = __builtin_amdgcn_mfma_f32_16x16x32_bf16(af[r], bfr[c], acc[r][c], 0, 0, 0);
        __syncthreads();
    }

    // epilogue: C/D layout col = lane&15, row = (lane>>4)*4 + i  [verified m89]
#pragma unroll
    for (int r = 0; r < 2; r++) {
        int grow_base = m0 + wr * 32 + r * 16 + kg * 4;
#pragma unroll
        for (int i = 0; i < 4; i++) {
            int grow = grow_base + i;
            if (grow < M) {
#pragma unroll
                for (int c = 0; c < 4; c++) {
                    int gcol = n0 + wc * 64 + c * 16 + l15;
                    float v = acc[r][c][i];
                    if (bias) v += bias[gcol];
                    C[(size_t)grow * Nout + gcol] = (OutT)v;
                }
            }
        }
    }
}

// ---------------- fused attention + aggregate + skip + LN + ReLU ----------------
// One wave per destination node. proj layout: q | k | v | skip at col offsets 0,256,512,768.
__global__ __launch_bounds__(256) void attn_kernel(const float* __restrict__ proj,
                                                   const __bf16* __restrict__ ebf,
                                                   const int* __restrict__ src,
                                                   const int* __restrict__ row_ptr,
                                                   const int* __restrict__ cidx,
                                                   const float* __restrict__ gamma,
                                                   const float* __restrict__ beta,
                                                   float* __restrict__ out) {
    int w = threadIdx.x >> 6, lane = threadIdx.x & 63;
    int d = blockIdx.x * 4 + w;
    if (d >= N_NODES) return;
    const float rscale = 0.08838834764831845f;  // 1/sqrt(128)

    f32x4 qv = *reinterpret_cast<const f32x4*>(proj + (size_t)d * 1024 + lane * 4);
    int start = row_ptr[d], end = row_ptr[d + 1];

    // pass 1: segment max of alpha (per head; lanes 0-31 = head0, 32-63 = head1)
    float m = -1e30f;
    for (int i = start; i < end; i++) {
        int eid = cidx[i];
        int s = src[eid];
        f32x4 kv = *reinterpret_cast<const f32x4*>(proj + (size_t)s * 1024 + 256 + lane * 4);
        bf16x4 ev = *reinterpret_cast<const bf16x4*>(ebf + (size_t)eid * 256 + lane * 4);
        float p = qv.x * (kv.x + (float)ev.x) + qv.y * (kv.y + (float)ev.y) +
                  qv.z * (kv.z + (float)ev.z) + qv.w * (kv.w + (float)ev.w);
#pragma unroll
        for (int o = 16; o > 0; o >>= 1) p += __shfl_xor(p, o, 32);
        m = fmaxf(m, p * rscale);
    }

    // pass 2: exp, denom, weighted aggregation of v[src]+e
    f32x4 acc = (f32x4)0.f;
    float den = 0.f;
    for (int i = start; i < end; i++) {
        int eid = cidx[i];
        int s = src[eid];
        const float* pr = proj + (size_t)s * 1024;
        f32x4 kv = *reinterpret_cast<const f32x4*>(pr + 256 + lane * 4);
        f32x4 vv = *reinterpret_cast<const f32x4*>(pr + 512 + lane * 4);
        bf16x4 ev = *reinterpret_cast<const bf16x4*>(ebf + (size_t)eid * 256 + lane * 4);
        float p = qv.x * (kv.x + (float)ev.x) + qv.y * (kv.y + (float)ev.y) +
                  qv.z * (kv.z + (float)ev.z) + qv.w * (kv.w + (float)ev.w);
#pragma unroll
        for (int o = 16; o > 0; o >>= 1) p += __shfl_xor(p, o, 32);
        float wgt = __expf(p * rscale - m);
        den += wgt;
        acc.x += wgt * (vv.x + (float)ev.x);
        acc.y += wgt * (vv.y + (float)ev.y);
        acc.z += wgt * (vv.z + (float)ev.z);
        acc.w += wgt * (vv.w + (float)ev.w);
    }

    float inv = 1.f / (den + 1e-16f);
    f32x4 sk = *reinterpret_cast<const f32x4*>(proj + (size_t)d * 1024 + 768 + lane * 4);
    f32x4 o;
    o.x = acc.x * inv + sk.x;
    o.y = acc.y * inv + sk.y;
    o.z = acc.z * inv + sk.z;
    o.w = acc.w * inv + sk.w;

    // LayerNorm over 256 channels (full-wave reduce)
    float s1 = o.x + o.y + o.z + o.w;
    float s2 = o.x * o.x + o.y * o.y + o.z * o.z + o.w * o.w;
#pragma unroll
    for (int off = 32; off > 0; off >>= 1) {
        s1 += __shfl_xor(s1, off, 64);
        s2 += __shfl_xor(s2, off, 64);
    }
    float mean = s1 * (1.f / 256.f);
    float var = s2 * (1.f / 256.f) - mean * mean;
    float rstd = rsqrtf(var + 1e-5f);
    f32x4 g = *reinterpret_cast<const f32x4*>(gamma + lane * 4);
    f32x4 b = *reinterpret_cast<const f32x4*>(beta + lane * 4);
    o.x = fmaxf(0.f, (o.x - mean) * rstd * g.x + b.x);
    o.y = fmaxf(0.f, (o.y - mean) * rstd * g.y + b.y);
    o.z = fmaxf(0.f, (o.z - mean) * rstd * g.z + b.z);
    o.w = fmaxf(0.f, (o.w - mean) * rstd * g.w + b.w);
    *reinterpret_cast<f32x4*>(out + (size_t)d * 256 + lane * 4) = o;
}

// ---------------- launch ----------------
extern "C" void kernel_launch(void* const* d_in, const int* in_sizes, int n_in,
                              void* d_out, int out_size, void* d_ws, size_t ws_size,
                              hipStream_t stream) {
    const float* x = (const float*)d_in[0];
    const float* edge_attr = (const float*)d_in[1];
    const int* edge_index = (const int*)d_in[2];
    const float* Wq = (const float*)d_in[3];
    const float* bq = (const float*)d_in[4];
    const float* Wk = (const float*)d_in[5];
    const float* bk = (const float*)d_in[6];
    const float* Wv = (const float*)d_in[7];
    const float* bv = (const float*)d_in[8];
    const float* We = (const float*)d_in[9];
    const float* Wskip = (const float*)d_in[10];
    const float* bskip = (const float*)d_in[11];
    const float* gamma = (const float*)d_in[12];
    const float* beta = (const float*)d_in[13];
    float* out = (float*)d_out;
    const int* src = edge_index;
    const int* dst = edge_index + N_EDGES;

    char* ws = (char*)d_ws;
    size_t off = 0;
    auto alloc = [&](size_t bytes) {
        size_t p = off;
        off += (bytes + 255) & ~(size_t)255;
        return p;
    };
    float* proj = (float*)(ws + alloc((size_t)N_NODES * 1024 * 4));
    __bf16* ebf = (__bf16*)(ws + alloc((size_t)N_EDGES * 256 * 2));
    __bf16* Wt_cat = (__bf16*)(ws + alloc(1024 * 256 * 2));
    __bf16* Wt_e = (__bf16*)(ws + alloc(256 * 256 * 2));
    float* bias_cat = (float*)(ws + alloc(1024 * 4));
    int* row_ptr = (int*)(ws + alloc((N_NODES + 1) * 4));
    int* cursor = (int*)(ws + alloc(N_NODES * 4));
    int* counts = (int*)(ws + alloc(N_NODES * 4));
    int* cidx = (int*)(ws + alloc(N_EDGES * 4));

    hipMemsetAsync(counts, 0, N_NODES * 4, stream);
    prep_weights_kernel<<<1280, 256, 0, stream>>>(Wq, bq, Wk, bk, Wv, bv, Wskip, bskip, We,
                                                  Wt_cat, bias_cat, Wt_e);
    count_kernel<<<(N_EDGES + 255) / 256, 256, 0, stream>>>(dst, counts);
    scan_kernel<<<1, 1024, 0, stream>>>(counts, row_ptr, cursor);
    scatter_kernel<<<(N_EDGES + 255) / 256, 256, 0, stream>>>(dst, cursor, cidx);
    gemm_kernel<float><<<dim3((N_NODES + BM - 1) / BM, 4), 512, 0, stream>>>(
        x, N_NODES, Wt_cat, bias_cat, 1024, proj);
    gemm_kernel<__bf16><<<dim3((N_EDGES + BM - 1) / BM, 1), 512, 0, stream>>>(
        edge_attr, N_EDGES, Wt_e, nullptr, 256, ebf);
    attn_kernel<<<(N_NODES + 3) / 4, 256, 0, stream>>>(proj, ebf, src, row_ptr, cidx,
                                                       gamma, beta, out);
}

// Round 2
// 554.704 us; speedup vs baseline: 1.1170x; 1.1170x over previous
//
#include <hip/hip_runtime.h>
#include <hip/hip_bf16.h>

#define N_NODES 50000
#define N_EDGES 300000
#define DIM 256

typedef __attribute__((ext_vector_type(4))) float f32x4;
typedef __attribute__((ext_vector_type(8))) __bf16 bf16x8;
typedef __attribute__((ext_vector_type(4))) __bf16 bf16x4;

// ---------------- weight prep: transpose + bf16 convert ----------------
// Wt_qs[n][k]: n<256 -> Wq col n ; n>=256 -> Wskip col n-256   (bias_qs likewise)
// Wt_kv[n][k]: n<256 -> Wk col n ; n>=256 -> Wv col n-256      (bias_kv likewise)
// Wt_e[n][k] = We[k][n]
__global__ void prep_weights_kernel(const float* __restrict__ Wq, const float* __restrict__ bq,
                                    const float* __restrict__ Wk, const float* __restrict__ bk,
                                    const float* __restrict__ Wv, const float* __restrict__ bv,
                                    const float* __restrict__ Wskip, const float* __restrict__ bskip,
                                    const float* __restrict__ We,
                                    __bf16* __restrict__ Wt_qs, float* __restrict__ bias_qs,
                                    __bf16* __restrict__ Wt_kv, float* __restrict__ bias_kv,
                                    __bf16* __restrict__ Wt_e) {
    int idx = blockIdx.x * 256 + threadIdx.x;
    if (idx < 512 * 256) {
        int n = idx >> 8, kk = idx & 255;
        const float* W = n < 256 ? Wq : Wskip;
        Wt_qs[idx] = (__bf16)W[kk * 256 + (n & 255)];
        if (kk == 0) bias_qs[n] = (n < 256 ? bq : bskip)[n & 255];
    } else if (idx < 1024 * 256) {
        int j = idx - 512 * 256;
        int n = j >> 8, kk = j & 255;
        const float* W = n < 256 ? Wk : Wv;
        Wt_kv[j] = (__bf16)W[kk * 256 + (n & 255)];
        if (kk == 0) bias_kv[n] = (n < 256 ? bk : bv)[n & 255];
    } else {
        int j = idx - 1024 * 256;
        if (j < 256 * 256) {
            int n = j >> 8, kk = j & 255;
            Wt_e[j] = (__bf16)We[kk * 256 + n];
        }
    }
}

// ---------------- CSR build ----------------
__global__ void count_kernel(const int* __restrict__ dst, int* __restrict__ counts) {
    int i = blockIdx.x * 256 + threadIdx.x;
    if (i < N_EDGES) atomicAdd(&counts[dst[i]], 1);
}

__global__ void scan_kernel(const int* __restrict__ counts, int* __restrict__ row_ptr,
                            int* __restrict__ cursor) {
    const int T = 1024;
    const int CPT = (N_NODES + T - 1) / T;  // 49
    int tid = threadIdx.x;
    int base = tid * CPT;
    int s = 0;
    for (int j = 0; j < CPT; j++) {
        int idx = base + j;
        if (idx < N_NODES) s += counts[idx];
    }
    __shared__ int buf[T];
    buf[tid] = s;
    __syncthreads();
    for (int off = 1; off < T; off <<= 1) {
        int t = (tid >= off) ? buf[tid - off] : 0;
        __syncthreads();
        buf[tid] += t;
        __syncthreads();
    }
    int run = buf[tid] - s;  // exclusive prefix for this chunk
    for (int j = 0; j < CPT; j++) {
        int idx = base + j;
        if (idx < N_NODES) {
            row_ptr[idx] = run;
            cursor[idx] = run;
            run += counts[idx];
        }
    }
    if (tid == T - 1) row_ptr[N_NODES] = run;
}

// scatter edges into CSR slots; also record the source node per slot
__global__ void scatter_kernel(const int* __restrict__ src, const int* __restrict__ dst,
                               int* __restrict__ cursor, int* __restrict__ cidx,
                               int* __restrict__ sperm) {
    int i = blockIdx.x * 256 + threadIdx.x;
    if (i < N_EDGES) {
        int p = atomicAdd(&cursor[dst[i]], 1);
        cidx[p] = i;
        sperm[p] = src[i];
    }
}

// ---------------- bf16 MFMA GEMM: C[M][Nout] = A[rowidx[M]][256] @ Wt^T (+bias) ----------------
// Wt is [Nout][256] (already transposed), bf16. A is f32, converted while staging.
// Tile: BM=64, BN=256, BK=32. 512 threads = 8 waves in 2x4 grid, each wave 32x64.
#define BM 64
#define BN 256
#define BK 32
#define KDIM 256

template <typename OutT>
__global__ __launch_bounds__(512) void gemm_kernel(const float* __restrict__ A,
                                                   const int* __restrict__ rowidx, int M,
                                                   const __bf16* __restrict__ Wt,
                                                   const float* __restrict__ bias, int Nout,
                                                   OutT* __restrict__ C) {
    __shared__ __bf16 As[BM][BK + 8];
    __shared__ __bf16 Bs[BN][BK + 8];
    int tid = threadIdx.x;
    int m0 = blockIdx.x * BM;
    int n0 = blockIdx.y * BN;
    int lane = tid & 63, w = tid >> 6;
    int wr = w >> 2, wc = w & 3;  // wave grid 2 x 4
    int l15 = lane & 15, kg = lane >> 4;

    f32x4 acc[2][4];
#pragma unroll
    for (int r = 0; r < 2; r++)
#pragma unroll
        for (int c = 0; c < 4; c++) acc[r][c] = (f32x4)0.f;

    int arow = tid >> 3, apart = tid & 7;  // A stage: 64 rows x 8 parts of 4 floats
    int brow = tid >> 1, bpart = tid & 1;  // B stage: 256 rows x 2 parts of 16 bf16
    bool aok = (m0 + arow) < M;
    int asrc = aok ? (rowidx ? rowidx[m0 + arow] : (m0 + arow)) : 0;
    const float* Aptr = A + (size_t)asrc * KDIM + apart * 4;
    const __bf16* Bptr = Wt + (size_t)(n0 + brow) * KDIM + bpart * 16;

    for (int k0 = 0; k0 < KDIM; k0 += BK) {
        f32x4 av = aok ? *reinterpret_cast<const f32x4*>(Aptr + k0) : (f32x4)0.f;
        bf16x4 ab;
        ab.x = (__bf16)av.x; ab.y = (__bf16)av.y; ab.z = (__bf16)av.z; ab.w = (__bf16)av.w;
        *reinterpret_cast<bf16x4*>(&As[arow][apart * 4]) = ab;

        bf16x8 b0 = *reinterpret_cast<const bf16x8*>(Bptr + k0);
        bf16x8 b1 = *reinterpret_cast<const bf16x8*>(Bptr + k0 + 8);
        *reinterpret_cast<bf16x8*>(&Bs[brow][bpart * 16]) = b0;
        *reinterpret_cast<bf16x8*>(&Bs[brow][bpart * 16 + 8]) = b1;
        __syncthreads();

        bf16x8 af[2], bfr[4];
#pragma unroll
        for (int r = 0; r < 2; r++)
            af[r] = *reinterpret_cast<const bf16x8*>(&As[wr * 32 + r * 16 + l15][kg * 8]);
#pragma unroll
        for (int c = 0; c < 4; c++)
            bfr[c] = *reinterpret_cast<const bf16x8*>(&Bs[wc * 64 + c * 16 + l15][kg * 8]);
#pragma unroll
        for (int r = 0; r < 2; r++)
#pragma unroll
            for (int c = 0; c < 4; c++)
                acc[r][c] = __builtin_amdgcn_mfma_f32_16x16x32_bf16(af[r], bfr[c], acc[r][c], 0, 0, 0);
        __syncthreads();
    }

    // epilogue: C/D layout col = lane&15, row = (lane>>4)*4 + i
#pragma unroll
    for (int r = 0; r < 2; r++) {
        int grow_base = m0 + wr * 32 + r * 16 + kg * 4;
#pragma unroll
        for (int i = 0; i < 4; i++) {
            int grow = grow_base + i;
            if (grow < M) {
#pragma unroll
                for (int c = 0; c < 4; c++) {
                    int gcol = n0 + wc * 64 + c * 16 + l15;
                    float v = acc[r][c][i];
                    if (bias) v += bias[gcol];
                    C[(size_t)grow * Nout + gcol] = (OutT)v;
                }
            }
        }
    }
}

// ---------------- fused attention (online softmax) + skip + LN + ReLU ----------------
// One wave per destination node.
// qs[node][512]: q at 0..255 (f32), skip at 256..511 (f32)
// kv[node][512]: k at 0..255 (bf16), v at 256..511 (bf16)
// eperm[slot][256] bf16 (CSR order), sperm[slot] = src node (CSR order)
__global__ __launch_bounds__(256) void attn_kernel(const float* __restrict__ qs,
                                                   const __bf16* __restrict__ kv,
                                                   const __bf16* __restrict__ eperm,
                                                   const int* __restrict__ sperm,
                                                   const int* __restrict__ row_ptr,
                                                   const float* __restrict__ gamma,
                                                   const float* __restrict__ beta,
                                                   float* __restrict__ out) {
    int w = threadIdx.x >> 6, lane = threadIdx.x & 63;
    int d = blockIdx.x * 4 + w;
    if (d >= N_NODES) return;
    const float rscale = 0.08838834764831845f;  // 1/sqrt(128)

    f32x4 q4 = *reinterpret_cast<const f32x4*>(qs + (size_t)d * 512 + lane * 4);
    int start = row_ptr[d], end = row_ptr[d + 1];

    float m = -1e30f, den = 0.f;
    f32x4 acc = (f32x4)0.f;
    for (int i = start; i < end; i++) {
        int s = sperm[i];
        const __bf16* kr = kv + (size_t)s * 512 + lane * 4;
        bf16x4 k4 = *reinterpret_cast<const bf16x4*>(kr);
        bf16x4 v4 = *reinterpret_cast<const bf16x4*>(kr + 256);
        bf16x4 e4 = *reinterpret_cast<const bf16x4*>(eperm + (size_t)i * 256 + lane * 4);
        float e0 = (float)e4.x, e1 = (float)e4.y, e2 = (float)e4.z, e3 = (float)e4.w;
        float p = q4.x * ((float)k4.x + e0) + q4.y * ((float)k4.y + e1) +
                  q4.z * ((float)k4.z + e2) + q4.w * ((float)k4.w + e3);
#pragma unroll
        for (int o = 16; o > 0; o >>= 1) p += __shfl_xor(p, o, 32);  // per-head reduce
        float alpha = p * rscale;
        float mn = fmaxf(m, alpha);
        float sc = __expf(m - mn);        // first iter: exp(-inf)=0
        float wt = __expf(alpha - mn);
        den = den * sc + wt;
        acc.x = acc.x * sc + wt * ((float)v4.x + e0);
        acc.y = acc.y * sc + wt * ((float)v4.y + e1);
        acc.z = acc.z * sc + wt * ((float)v4.z + e2);
        acc.w = acc.w * sc + wt * ((float)v4.w + e3);
        m = mn;
    }

    float inv = 1.f / (den + 1e-16f);
    f32x4 sk = *reinterpret_cast<const f32x4*>(qs + (size_t)d * 512 + 256 + lane * 4);
    f32x4 o;
    o.x = acc.x * inv + sk.x;
    o.y = acc.y * inv + sk.y;
    o.z = acc.z * inv + sk.z;
    o.w = acc.w * inv + sk.w;

    // LayerNorm over 256 channels (full-wave reduce)
    float s1 = o.x + o.y + o.z + o.w;
    float s2 = o.x * o.x + o.y * o.y + o.z * o.z + o.w * o.w;
#pragma unroll
    for (int off = 32; off > 0; off >>= 1) {
        s1 += __shfl_xor(s1, off, 64);
        s2 += __shfl_xor(s2, off, 64);
    }
    float mean = s1 * (1.f / 256.f);
    float var = s2 * (1.f / 256.f) - mean * mean;
    float rstd = rsqrtf(var + 1e-5f);
    f32x4 g = *reinterpret_cast<const f32x4*>(gamma + lane * 4);
    f32x4 b = *reinterpret_cast<const f32x4*>(beta + lane * 4);
    o.x = fmaxf(0.f, (o.x - mean) * rstd * g.x + b.x);
    o.y = fmaxf(0.f, (o.y - mean) * rstd * g.y + b.y);
    o.z = fmaxf(0.f, (o.z - mean) * rstd * g.z + b.z);
    o.w = fmaxf(0.f, (o.w - mean) * rstd * g.w + b.w);
    *reinterpret_cast<f32x4*>(out + (size_t)d * 256 + lane * 4) = o;
}

// ---------------- launch ----------------
extern "C" void kernel_launch(void* const* d_in, const int* in_sizes, int n_in,
                              void* d_out, int out_size, void* d_ws, size_t ws_size,
                              hipStream_t stream) {
    const float* x = (const float*)d_in[0];
    const float* edge_attr = (const float*)d_in[1];
    const int* edge_index = (const int*)d_in[2];
    const float* Wq = (const float*)d_in[3];
    const float* bq = (const float*)d_in[4];
    const float* Wk = (const float*)d_in[5];
    const float* bk = (const float*)d_in[6];
    const float* Wv = (const float*)d_in[7];
    const float* bv = (const float*)d_in[8];
    const float* We = (const float*)d_in[9];
    const float* Wskip = (const float*)d_in[10];
    const float* bskip = (const float*)d_in[11];
    const float* gamma = (const float*)d_in[12];
    const float* beta = (const float*)d_in[13];
    float* out = (float*)d_out;
    const int* src = edge_index;
    const int* dst = edge_index + N_EDGES;

    char* ws = (char*)d_ws;
    size_t off = 0;
    auto alloc = [&](size_t bytes) {
        size_t p = off;
        off += (bytes + 255) & ~(size_t)255;
        return p;
    };
    float* qs = (float*)(ws + alloc((size_t)N_NODES * 512 * 4));
    __bf16* kvb = (__bf16*)(ws + alloc((size_t)N_NODES * 512 * 2));
    __bf16* eperm = (__bf16*)(ws + alloc((size_t)N_EDGES * 256 * 2));
    __bf16* Wt_qs = (__bf16*)(ws + alloc(512 * 256 * 2));
    __bf16* Wt_kv = (__bf16*)(ws + alloc(512 * 256 * 2));
    __bf16* Wt_e = (__bf16*)(ws + alloc(256 * 256 * 2));
    float* bias_qs = (float*)(ws + alloc(512 * 4));
    float* bias_kv = (float*)(ws + alloc(512 * 4));
    int* row_ptr = (int*)(ws + alloc((N_NODES + 1) * 4));
    int* cursor = (int*)(ws + alloc(N_NODES * 4));
    int* counts = (int*)(ws + alloc(N_NODES * 4));
    int* cidx = (int*)(ws + alloc(N_EDGES * 4));
    int* sperm = (int*)(ws + alloc(N_EDGES * 4));

    hipMemsetAsync(counts, 0, N_NODES * 4, stream);
    prep_weights_kernel<<<1280, 256, 0, stream>>>(Wq, bq, Wk, bk, Wv, bv, Wskip, bskip, We,
                                                  Wt_qs, bias_qs, Wt_kv, bias_kv, Wt_e);
    count_kernel<<<(N_EDGES + 255) / 256, 256, 0, stream>>>(dst, counts);
    scan_kernel<<<1, 1024, 0, stream>>>(counts, row_ptr, cursor);
    scatter_kernel<<<(N_EDGES + 255) / 256, 256, 0, stream>>>(src, dst, cursor, cidx, sperm);
    gemm_kernel<float><<<dim3((N_NODES + BM - 1) / BM, 2), 512, 0, stream>>>(
        x, nullptr, N_NODES, Wt_qs, bias_qs, 512, qs);
    gemm_kernel<__bf16><<<dim3((N_NODES + BM - 1) / BM, 2), 512, 0, stream>>>(
        x, nullptr, N_NODES, Wt_kv, bias_kv, 512, kvb);
    gemm_kernel<__bf16><<<dim3((N_EDGES + BM - 1) / BM, 1), 512, 0, stream>>>(
        edge_attr, cidx, N_EDGES, Wt_e, nullptr, 256, eperm);
    attn_kernel<<<(N_NODES + 3) / 4, 256, 0, stream>>>(qs, kvb, eperm, sperm, row_ptr,
                                                       gamma, beta, out);
}

// Round 3
// 445.572 us; speedup vs baseline: 1.3906x; 1.2449x over previous
//
#include <hip/hip_runtime.h>
#include <hip/hip_bf16.h>

#define N_NODES 50000
#define N_EDGES 300000

typedef __attribute__((ext_vector_type(4))) float f32x4;
typedef __attribute__((ext_vector_type(8))) __bf16 bf16x8;
typedef __attribute__((ext_vector_type(4))) __bf16 bf16x4;

// ---------------- weight prep: transpose + bf16 + MFMA-fragment swizzle ----------------
// Swizzled layout: element for (output col n, k) lives at
//   [ ((nb*8 + step)*1024 + (n&255)*4 + kg)*8 + j ]
// with nb=n>>8 (0=q,1=k,2=v,3=skip), step=k>>5, kg=(k>>3)&3, j=k&7.
// GEMM B-staging then copies 16 KB/step contiguously; ds_read_b128 fragment
// reads cover contiguous 1 KB per wave -> zero bank conflicts.
__global__ void prep_weights_kernel(const float* __restrict__ Wq, const float* __restrict__ bq,
                                    const float* __restrict__ Wk, const float* __restrict__ bk,
                                    const float* __restrict__ Wv, const float* __restrict__ bv,
                                    const float* __restrict__ Wskip, const float* __restrict__ bskip,
                                    const float* __restrict__ We,
                                    __bf16* __restrict__ Wp, float* __restrict__ bias_p,
                                    __bf16* __restrict__ Wes) {
    int idx = blockIdx.x * 256 + threadIdx.x;
    if (idx < 1024 * 256) {
        int k = idx >> 10, n = idx & 1023;  // consecutive threads: consecutive n (coalesced read)
        int nb = n >> 8, nn = n & 255;
        const float* W = nb == 0 ? Wq : nb == 1 ? Wk : nb == 2 ? Wv : Wskip;
        int step = k >> 5, kg = (k >> 3) & 3, j = k & 7;
        Wp[(((nb * 8 + step) * 1024) + nn * 4 + kg) * 8 + j] = (__bf16)W[k * 256 + nn];
        if (k == 0) {
            const float* b = nb == 0 ? bq : nb == 1 ? bk : nb == 2 ? bv : bskip;
            bias_p[n] = b[nn];
        }
    } else {
        int r = idx - 1024 * 256;
        if (r < 256 * 256) {
            int k = r >> 8, n = r & 255;
            int step = k >> 5, kg = (k >> 3) & 3, j = k & 7;
            Wes[((step * 1024) + n * 4 + kg) * 8 + j] = (__bf16)We[k * 256 + n];
        }
    }
}

// ---------------- CSR build ----------------
__global__ void count_kernel(const int* __restrict__ dst, int* __restrict__ counts) {
    int i = blockIdx.x * 256 + threadIdx.x;
    if (i < N_EDGES) atomicAdd(&counts[dst[i]], 1);
}

__global__ void scan_kernel(const int* __restrict__ counts, int* __restrict__ row_ptr,
                            int* __restrict__ cursor) {
    const int T = 1024;
    const int CPT = (N_NODES + T - 1) / T;  // 49
    int tid = threadIdx.x;
    int base = tid * CPT;
    int s = 0;
    for (int j = 0; j < CPT; j++) {
        int idx = base + j;
        if (idx < N_NODES) s += counts[idx];
    }
    __shared__ int buf[T];
    buf[tid] = s;
    __syncthreads();
    for (int off = 1; off < T; off <<= 1) {
        int t = (tid >= off) ? buf[tid - off] : 0;
        __syncthreads();
        buf[tid] += t;
        __syncthreads();
    }
    int run = buf[tid] - s;
    for (int j = 0; j < CPT; j++) {
        int idx = base + j;
        if (idx < N_NODES) {
            row_ptr[idx] = run;
            cursor[idx] = run;
            run += counts[idx];
        }
    }
    if (tid == T - 1) row_ptr[N_NODES] = run;
}

__global__ void scatter_kernel(const int* __restrict__ src, const int* __restrict__ dst,
                               int* __restrict__ cursor, int* __restrict__ cidx,
                               int* __restrict__ sperm) {
    int i = blockIdx.x * 256 + threadIdx.x;
    if (i < N_EDGES) {
        int p = atomicAdd(&cursor[dst[i]], 1);
        cidx[p] = i;
        sperm[p] = src[i];
    }
}

// ---------------- bf16 MFMA GEMM ----------------
// C[M][Nout] = A[rowidx[M]][256] @ W^T (+bias). W pre-swizzled (see prep).
// BM=128, BN=256, BK=32, 512 threads = 8 waves (2x4), wave tile 64x64.
// LDS fragment-contiguous: slot = row*4+kg, 16B each -> conflict-free b128 r/w.
// Double-buffered, one barrier per K-step; step k+1 globals issued before MFMA.
#define BM 128
#define BN 256
#define KD 256

template <typename OutT>
__global__ __launch_bounds__(512, 4) void gemm_kernel(const float* __restrict__ A,
                                                      const int* __restrict__ rowidx, int M,
                                                      const __bf16* __restrict__ Wswz,
                                                      const float* __restrict__ bias, int Nout,
                                                      OutT* __restrict__ C) {
    __shared__ __bf16 As[2][BM * 4 * 8];   // 8 KB per buffer
    __shared__ __bf16 Bs[2][BN * 4 * 8];   // 16 KB per buffer
    int tid = threadIdx.x;
    int m0 = blockIdx.x * BM;
    int nb = blockIdx.y;
    int lane = tid & 63, w = tid >> 6;
    int wr = w >> 2, wc = w & 3;            // wave grid 2 x 4
    int l15 = lane & 15, kg4 = lane >> 4;   // fragment lane decomposition

    f32x4 acc[4][4];
#pragma unroll
    for (int r = 0; r < 4; r++)
#pragma unroll
        for (int c = 0; c < 4; c++) acc[r][c] = (f32x4)0.f;

    // staging: A thread -> (row=tid>>2, kg=tid&3): two f32x4, one b128 LDS write at slot tid
    int arow = tid >> 2, apart = tid & 3;
    bool aok = (m0 + arow) < M;
    int asrc = aok ? (rowidx ? rowidx[m0 + arow] : (m0 + arow)) : 0;
    const float* Aptr = A + (size_t)asrc * KD + apart * 8;
    const __bf16* Bbase = Wswz + (size_t)nb * 8 * 8192;  // nb-block: 8 steps x 8192 elems

    // prologue: stage step 0 into buffer 0
    f32x4 a0 = aok ? *reinterpret_cast<const f32x4*>(Aptr) : (f32x4)0.f;
    f32x4 a1 = aok ? *reinterpret_cast<const f32x4*>(Aptr + 4) : (f32x4)0.f;
    bf16x8 b0 = *reinterpret_cast<const bf16x8*>(Bbase + (size_t)tid * 8);
    bf16x8 b1 = *reinterpret_cast<const bf16x8*>(Bbase + (size_t)(tid + 512) * 8);
    {
        bf16x8 ab;
        ab[0] = (__bf16)a0.x; ab[1] = (__bf16)a0.y; ab[2] = (__bf16)a0.z; ab[3] = (__bf16)a0.w;
        ab[4] = (__bf16)a1.x; ab[5] = (__bf16)a1.y; ab[6] = (__bf16)a1.z; ab[7] = (__bf16)a1.w;
        *reinterpret_cast<bf16x8*>(&As[0][tid * 8]) = ab;
        *reinterpret_cast<bf16x8*>(&Bs[0][tid * 8]) = b0;
        *reinterpret_cast<bf16x8*>(&Bs[0][(tid + 512) * 8]) = b1;
    }
    __syncthreads();

    int s = 0;
#pragma unroll
    for (int step = 0; step < 8; ++step) {
        if (step < 7) {  // issue next-step globals early (latency hides under MFMA)
            int k0 = (step + 1) * 32;
            a0 = aok ? *reinterpret_cast<const f32x4*>(Aptr + k0) : (f32x4)0.f;
            a1 = aok ? *reinterpret_cast<const f32x4*>(Aptr + k0 + 4) : (f32x4)0.f;
            b0 = *reinterpret_cast<const bf16x8*>(Bbase + (size_t)((step + 1) * 8192 + tid * 8));
            b1 = *reinterpret_cast<const bf16x8*>(Bbase + (size_t)((step + 1) * 8192 + (tid + 512) * 8));
        }
        bf16x8 af[4], bfr[4];
#pragma unroll
        for (int r = 0; r < 4; r++)
            af[r] = *reinterpret_cast<const bf16x8*>(&As[s][((wr * 64 + r * 16 + l15) * 4 + kg4) * 8]);
#pragma unroll
        for (int c = 0; c < 4; c++)
            bfr[c] = *reinterpret_cast<const bf16x8*>(&Bs[s][((wc * 64 + c * 16 + l15) * 4 + kg4) * 8]);
#pragma unroll
        for (int r = 0; r < 4; r++)
#pragma unroll
            for (int c = 0; c < 4; c++)
                acc[r][c] = __builtin_amdgcn_mfma_f32_16x16x32_bf16(af[r], bfr[c], acc[r][c], 0, 0, 0);
        if (step < 7) {  // write next step into ping-pong buffer (nobody reads it this step)
            bf16x8 ab;
            ab[0] = (__bf16)a0.x; ab[1] = (__bf16)a0.y; ab[2] = (__bf16)a0.z; ab[3] = (__bf16)a0.w;
            ab[4] = (__bf16)a1.x; ab[5] = (__bf16)a1.y; ab[6] = (__bf16)a1.z; ab[7] = (__bf16)a1.w;
            *reinterpret_cast<bf16x8*>(&As[s ^ 1][tid * 8]) = ab;
            *reinterpret_cast<bf16x8*>(&Bs[s ^ 1][tid * 8]) = b0;
            *reinterpret_cast<bf16x8*>(&Bs[s ^ 1][(tid + 512) * 8]) = b1;
        }
        __syncthreads();
        s ^= 1;
    }

    // epilogue: C/D layout col = lane&15, row = (lane>>4)*4 + i
#pragma unroll
    for (int r = 0; r < 4; r++) {
        int grow_base = m0 + wr * 64 + r * 16 + kg4 * 4;
#pragma unroll
        for (int i = 0; i < 4; i++) {
            int grow = grow_base + i;
            if (grow < M) {
#pragma unroll
                for (int c = 0; c < 4; c++) {
                    int gcol = nb * BN + wc * 64 + c * 16 + l15;
                    float v = acc[r][c][i];
                    if (bias) v += bias[gcol];
                    C[(size_t)grow * Nout + gcol] = (OutT)v;
                }
            }
        }
    }
}

// ---------------- fused attention (online softmax, 2-edge ILP) + skip + LN + ReLU ----------------
// proj[node][1024] bf16: q|k|v|skip at 0/256/512/768. One wave per destination node.
__global__ __launch_bounds__(256) void attn_kernel(const __bf16* __restrict__ proj,
                                                   const __bf16* __restrict__ eperm,
                                                   const int* __restrict__ sperm,
                                                   const int* __restrict__ row_ptr,
                                                   const float* __restrict__ gamma,
                                                   const float* __restrict__ beta,
                                                   float* __restrict__ out) {
    int w = threadIdx.x >> 6, lane = threadIdx.x & 63;
    int d = blockIdx.x * 4 + w;
    if (d >= N_NODES) return;
    const float rscale = 0.08838834764831845f;  // 1/sqrt(128)

    bf16x4 qb = *reinterpret_cast<const bf16x4*>(proj + (size_t)d * 1024 + lane * 4);
    float q0 = (float)qb.x, q1 = (float)qb.y, q2 = (float)qb.z, q3 = (float)qb.w;
    int start = row_ptr[d], end = row_ptr[d + 1];

    float m = -1e30f, den = 0.f;
    f32x4 acc = (f32x4)0.f;
    int i = start;
    for (; i + 1 < end; i += 2) {
        int s0 = sperm[i], s1 = sperm[i + 1];
        const __bf16* p0 = proj + (size_t)s0 * 1024 + 256 + lane * 4;
        const __bf16* p1 = proj + (size_t)s1 * 1024 + 256 + lane * 4;
        bf16x4 k0 = *reinterpret_cast<const bf16x4*>(p0);
        bf16x4 v0 = *reinterpret_cast<const bf16x4*>(p0 + 256);
        bf16x4 k1 = *reinterpret_cast<const bf16x4*>(p1);
        bf16x4 v1 = *reinterpret_cast<const bf16x4*>(p1 + 256);
        bf16x4 e0 = *reinterpret_cast<const bf16x4*>(eperm + (size_t)i * 256 + lane * 4);
        bf16x4 e1 = *reinterpret_cast<const bf16x4*>(eperm + (size_t)(i + 1) * 256 + lane * 4);
        float e0x = (float)e0.x, e0y = (float)e0.y, e0z = (float)e0.z, e0w = (float)e0.w;
        float e1x = (float)e1.x, e1y = (float)e1.y, e1z = (float)e1.z, e1w = (float)e1.w;
        float pa = q0 * ((float)k0.x + e0x) + q1 * ((float)k0.y + e0y) +
                   q2 * ((float)k0.z + e0z) + q3 * ((float)k0.w + e0w);
        float pb = q0 * ((float)k1.x + e1x) + q1 * ((float)k1.y + e1y) +
                   q2 * ((float)k1.z + e1z) + q3 * ((float)k1.w + e1w);
#pragma unroll
        for (int o = 16; o > 0; o >>= 1) {
            pa += __shfl_xor(pa, o, 32);
            pb += __shfl_xor(pb, o, 32);
        }
        float A0 = pa * rscale, A1 = pb * rscale;
        float mn = fmaxf(m, fmaxf(A0, A1));
        float sc = __expf(m - mn);
        float w0 = __expf(A0 - mn), w1 = __expf(A1 - mn);
        den = den * sc + w0 + w1;
        acc.x = acc.x * sc + w0 * ((float)v0.x + e0x) + w1 * ((float)v1.x + e1x);
        acc.y = acc.y * sc + w0 * ((float)v0.y + e0y) + w1 * ((float)v1.y + e1y);
        acc.z = acc.z * sc + w0 * ((float)v0.z + e0z) + w1 * ((float)v1.z + e1z);
        acc.w = acc.w * sc + w0 * ((float)v0.w + e0w) + w1 * ((float)v1.w + e1w);
        m = mn;
    }
    if (i < end) {
        int s0 = sperm[i];
        const __bf16* p0 = proj + (size_t)s0 * 1024 + 256 + lane * 4;
        bf16x4 k0 = *reinterpret_cast<const bf16x4*>(p0);
        bf16x4 v0 = *reinterpret_cast<const bf16x4*>(p0 + 256);
        bf16x4 e0 = *reinterpret_cast<const bf16x4*>(eperm + (size_t)i * 256 + lane * 4);
        float e0x = (float)e0.x, e0y = (float)e0.y, e0z = (float)e0.z, e0w = (float)e0.w;
        float pa = q0 * ((float)k0.x + e0x) + q1 * ((float)k0.y + e0y) +
                   q2 * ((float)k0.z + e0z) + q3 * ((float)k0.w + e0w);
#pragma unroll
        for (int o = 16; o > 0; o >>= 1) pa += __shfl_xor(pa, o, 32);
        float A0 = pa * rscale;
        float mn = fmaxf(m, A0);
        float sc = __expf(m - mn), w0 = __expf(A0 - mn);
        den = den * sc + w0;
        acc.x = acc.x * sc + w0 * ((float)v0.x + e0x);
        acc.y = acc.y * sc + w0 * ((float)v0.y + e0y);
        acc.z = acc.z * sc + w0 * ((float)v0.z + e0z);
        acc.w = acc.w * sc + w0 * ((float)v0.w + e0w);
    }

    float inv = 1.f / (den + 1e-16f);
    bf16x4 skb = *reinterpret_cast<const bf16x4*>(proj + (size_t)d * 1024 + 768 + lane * 4);
    f32x4 o;
    o.x = acc.x * inv + (float)skb.x;
    o.y = acc.y * inv + (float)skb.y;
    o.z = acc.z * inv + (float)skb.z;
    o.w = acc.w * inv + (float)skb.w;

    // LayerNorm over 256 channels (full-wave reduce)
    float s1 = o.x + o.y + o.z + o.w;
    float s2 = o.x * o.x + o.y * o.y + o.z * o.z + o.w * o.w;
#pragma unroll
    for (int off = 32; off > 0; off >>= 1) {
        s1 += __shfl_xor(s1, off, 64);
        s2 += __shfl_xor(s2, off, 64);
    }
    float mean = s1 * (1.f / 256.f);
    float var = s2 * (1.f / 256.f) - mean * mean;
    float rstd = rsqrtf(var + 1e-5f);
    f32x4 g = *reinterpret_cast<const f32x4*>(gamma + lane * 4);
    f32x4 b = *reinterpret_cast<const f32x4*>(beta + lane * 4);
    o.x = fmaxf(0.f, (o.x - mean) * rstd * g.x + b.x);
    o.y = fmaxf(0.f, (o.y - mean) * rstd * g.y + b.y);
    o.z = fmaxf(0.f, (o.z - mean) * rstd * g.z + b.z);
    o.w = fmaxf(0.f, (o.w - mean) * rstd * g.w + b.w);
    *reinterpret_cast<f32x4*>(out + (size_t)d * 256 + lane * 4) = o;
}

// ---------------- launch ----------------
extern "C" void kernel_launch(void* const* d_in, const int* in_sizes, int n_in,
                              void* d_out, int out_size, void* d_ws, size_t ws_size,
                              hipStream_t stream) {
    const float* x = (const float*)d_in[0];
    const float* edge_attr = (const float*)d_in[1];
    const int* edge_index = (const int*)d_in[2];
    const float* Wq = (const float*)d_in[3];
    const float* bq = (const float*)d_in[4];
    const float* Wk = (const float*)d_in[5];
    const float* bk = (const float*)d_in[6];
    const float* Wv = (const float*)d_in[7];
    const float* bv = (const float*)d_in[8];
    const float* We = (const float*)d_in[9];
    const float* Wskip = (const float*)d_in[10];
    const float* bskip = (const float*)d_in[11];
    const float* gamma = (const float*)d_in[12];
    const float* beta = (const float*)d_in[13];
    float* out = (float*)d_out;
    const int* src = edge_index;
    const int* dst = edge_index + N_EDGES;

    char* ws = (char*)d_ws;
    size_t off = 0;
    auto alloc = [&](size_t bytes) {
        size_t p = off;
        off += (bytes + 255) & ~(size_t)255;
        return p;
    };
    __bf16* proj = (__bf16*)(ws + alloc((size_t)N_NODES * 1024 * 2));
    __bf16* eperm = (__bf16*)(ws + alloc((size_t)N_EDGES * 256 * 2));
    __bf16* Wp = (__bf16*)(ws + alloc(1024 * 256 * 2));
    __bf16* Wes = (__bf16*)(ws + alloc(256 * 256 * 2));
    float* bias_p = (float*)(ws + alloc(1024 * 4));
    int* row_ptr = (int*)(ws + alloc((N_NODES + 1) * 4));
    int* cursor = (int*)(ws + alloc(N_NODES * 4));
    int* counts = (int*)(ws + alloc(N_NODES * 4));
    int* cidx = (int*)(ws + alloc(N_EDGES * 4));
    int* sperm = (int*)(ws + alloc(N_EDGES * 4));

    hipMemsetAsync(counts, 0, N_NODES * 4, stream);
    prep_weights_kernel<<<1280, 256, 0, stream>>>(Wq, bq, Wk, bk, Wv, bv, Wskip, bskip, We,
                                                  Wp, bias_p, Wes);
    count_kernel<<<(N_EDGES + 255) / 256, 256, 0, stream>>>(dst, counts);
    scan_kernel<<<1, 1024, 0, stream>>>(counts, row_ptr, cursor);
    scatter_kernel<<<(N_EDGES + 255) / 256, 256, 0, stream>>>(src, dst, cursor, cidx, sperm);
    gemm_kernel<__bf16><<<dim3((N_NODES + BM - 1) / BM, 4), 512, 0, stream>>>(
        x, nullptr, N_NODES, Wp, bias_p, 1024, proj);
    gemm_kernel<__bf16><<<dim3((N_EDGES + BM - 1) / BM, 1), 512, 0, stream>>>(
        edge_attr, cidx, N_EDGES, Wes, nullptr, 256, eperm);
    attn_kernel<<<(N_NODES + 3) / 4, 256, 0, stream>>>(proj, eperm, sperm, row_ptr,
                                                       gamma, beta, out);
}